// Round 1
// baseline (4502.165 us; speedup 1.0000x reference)
//
#include <hip/hip_runtime.h>
#include <hip/hip_bf16.h>

// Problem constants (from reference)
#define NN 100000      // nodes
#define NE 1600000     // edges
#define KF 128         // in feats == hidden
#define F1 128         // layer-1 out feats
#define F2 64          // layer-2 out feats

// ---------------------------------------------------------------------------
// degree accumulation: deg_out[src[e]] += 1, deg_in[dst[e]] += 1
__global__ __launch_bounds__(256) void degree_kernel(
    const int* __restrict__ src, const int* __restrict__ dst,
    float* __restrict__ degO, float* __restrict__ degI, int n)
{
    int i = blockIdx.x * 256 + threadIdx.x;
    if (i < n) {
        atomicAdd(&degO[src[i]], 1.0f);
        atomicAdd(&degI[dst[i]], 1.0f);
    }
}

// deg -> rsqrt(max(deg,1))
__global__ __launch_bounds__(256) void rsqrt_kernel(
    float* __restrict__ degO, float* __restrict__ degI, int n)
{
    int i = blockIdx.x * 256 + threadIdx.x;
    if (i < n) {
        degO[i] = rsqrtf(fmaxf(degO[i], 1.0f));
        degI[i] = rsqrtf(fmaxf(degI[i], 1.0f));
    }
}

// ---------------------------------------------------------------------------
// H[i,j] = scale[i] * sum_k X[i,k] * W[k,j]     (K = 128 fixed)
// block = 256 threads, 16 rows per block. W staged in LDS, X tile in LDS.
template<int NOUT>
__global__ __launch_bounds__(256) void gemm_scale(
    const float* __restrict__ X,     // [N, 128]
    const float* __restrict__ W,     // [128, NOUT]
    const float* __restrict__ scale, // [N]  (deg_out^-1/2)
    float* __restrict__ H,           // [N, NOUT]
    int nrows)
{
    constexpr int K = KF;
    constexpr int ROWS = 16;
    __shared__ float Wl[K * NOUT];
    __shared__ float Xs[ROWS * K];

    const int tid = threadIdx.x;
    for (int i = tid; i < K * NOUT; i += 256) Wl[i] = W[i];

    const int row0 = blockIdx.x * ROWS;
    const float4* X4 = reinterpret_cast<const float4*>(X + (size_t)row0 * K);
    float4* Xs4 = reinterpret_cast<float4*>(Xs);
    #pragma unroll
    for (int i = tid; i < ROWS * K / 4; i += 256) Xs4[i] = X4[i];
    __syncthreads();

    constexpr int RPP = 256 / NOUT;   // rows in flight per pass: 2 (NOUT=128) / 4 (NOUT=64)
    constexpr int NACC = ROWS / RPP;  // accumulators per thread: 8 / 4
    const int j  = tid % NOUT;
    const int r0 = tid / NOUT;

    float acc[NACC];
    #pragma unroll
    for (int a = 0; a < NACC; ++a) acc[a] = 0.0f;

    #pragma unroll 4
    for (int k = 0; k < K; ++k) {
        float w = Wl[k * NOUT + j];
        #pragma unroll
        for (int a = 0; a < NACC; ++a)
            acc[a] += Xs[(r0 + a * RPP) * K + k] * w;
    }

    #pragma unroll
    for (int a = 0; a < NACC; ++a) {
        int r = row0 + r0 + a * RPP;
        if (r < nrows)
            H[(size_t)r * NOUT + j] = acc[a] * scale[r];
    }
}

// ---------------------------------------------------------------------------
// scatter: AGG[dst[e], :] += H[src[e], :]   (atomic f32, float4 granularity)
// F4 = feats/4 (power of two)
template<int F4>
__global__ __launch_bounds__(256) void scatter_add(
    const float* __restrict__ H, const int* __restrict__ src,
    const int* __restrict__ dst, float* __restrict__ AGG,
    unsigned int total)
{
    unsigned int idx = blockIdx.x * 256u + threadIdx.x;
    const unsigned int stride = gridDim.x * 256u;
    for (; idx < total; idx += stride) {
        const unsigned int e = idx / F4;      // constexpr pow2 -> shift
        const unsigned int f = idx % F4;
        const int s = src[e];
        const int d = dst[e];
        const float4 v = reinterpret_cast<const float4*>(H)[(size_t)s * F4 + f];
        float* o = AGG + ((size_t)d * F4 + f) * 4;
        atomicAdd(o + 0, v.x);
        atomicAdd(o + 1, v.y);
        atomicAdd(o + 2, v.z);
        atomicAdd(o + 3, v.w);
    }
}

// ---------------------------------------------------------------------------
// A[i,j] = (A[i,j] * deg[i] + b[j])  (+ optional relu), in place, float4 wide
template<int F4, bool RELU>
__global__ __launch_bounds__(256) void bias_scale(
    float* __restrict__ A, const float* __restrict__ deg,
    const float* __restrict__ b, int nnodes)
{
    int idx = blockIdx.x * 256 + threadIdx.x;
    const int total = nnodes * F4;
    if (idx >= total) return;
    const int i = idx / F4;
    const int f = idx % F4;
    const float s = deg[i];
    float4 v = reinterpret_cast<float4*>(A)[idx];
    const float4 bb = reinterpret_cast<const float4*>(b)[f];
    v.x = v.x * s + bb.x;
    v.y = v.y * s + bb.y;
    v.z = v.z * s + bb.z;
    v.w = v.w * s + bb.w;
    if (RELU) {
        v.x = fmaxf(v.x, 0.0f);
        v.y = fmaxf(v.y, 0.0f);
        v.z = fmaxf(v.z, 0.0f);
        v.w = fmaxf(v.w, 0.0f);
    }
    reinterpret_cast<float4*>(A)[idx] = v;
}

// ---------------------------------------------------------------------------
extern "C" void kernel_launch(void* const* d_in, const int* in_sizes, int n_in,
                              void* d_out, int out_size, void* d_ws, size_t ws_size,
                              hipStream_t stream)
{
    const float* x  = (const float*)d_in[0];
    const int*   src = (const int*)d_in[1];
    const int*   dst = (const int*)d_in[2];
    const float* W1 = (const float*)d_in[3];
    const float* b1 = (const float*)d_in[4];
    const float* W2 = (const float*)d_in[5];
    const float* b2 = (const float*)d_in[6];
    float* out = (float*)d_out;

    // workspace layout (floats)
    float* ws   = (float*)d_ws;
    float* degO = ws;                     // 100352 (padded)
    float* degI = ws + 100352;            // 100352
    float* h1   = ws + 2 * 100352;        // 12.8M   (layer-1 pre-agg; reused as h2)
    float* agg1 = h1 + (size_t)NN * F1;   // 12.8M   (layer-1 agg -> hidden)
    float* h2   = h1;                     // overlay: h1 dead after layer-1 scatter

    // zero the accumulators (harness poisons d_ws/d_out with 0xAA)
    hipMemsetAsync(degO, 0, 2 * 100352 * sizeof(float), stream);
    hipMemsetAsync(agg1, 0, (size_t)NN * F1 * sizeof(float), stream);
    hipMemsetAsync(out,  0, (size_t)NN * F2 * sizeof(float), stream);

    // degrees
    degree_kernel<<<(NE + 255) / 256, 256, 0, stream>>>(src, dst, degO, degI, NE);
    rsqrt_kernel<<<(NN + 255) / 256, 256, 0, stream>>>(degO, degI, NN);

    // layer 1: h1 = (x @ W1) * degO ; agg1 += scatter ; hidden = relu(agg1*degI + b1)
    gemm_scale<F1><<<NN / 16, 256, 0, stream>>>(x, W1, degO, h1, NN);
    scatter_add<F1 / 4><<<8192, 256, 0, stream>>>(h1, src, dst, agg1,
                                                  (unsigned)NE * (F1 / 4));
    bias_scale<F1 / 4, true><<<(NN * (F1 / 4) + 255) / 256, 256, 0, stream>>>(
        agg1, degI, b1, NN);

    // layer 2: h2 = (hidden @ W2) * degO ; out += scatter ; out = out*degI + b2
    gemm_scale<F2><<<NN / 16, 256, 0, stream>>>(agg1, W2, degO, h2, NN);
    scatter_add<F2 / 4><<<8192, 256, 0, stream>>>(h2, src, dst, out,
                                                  (unsigned)NE * (F2 / 4));
    bias_scale<F2 / 4, false><<<(NN * (F2 / 4) + 255) / 256, 256, 0, stream>>>(
        out, degI, b2, NN);
}

// Round 5
// 700.404 us; speedup vs baseline: 6.4280x; 6.4280x over previous
//
#include <hip/hip_runtime.h>
#include <hip/hip_bf16.h>

// Problem constants (from reference)
#define NN 100000      // nodes
#define NE 1600000     // edges
#define KF 128         // in feats == hidden
#define F1 128         // layer-1 out feats
#define F2 64          // layer-2 out feats

#define SCAN_ELEMS 1024                      // elements per scan block
#define SCAN_NB ((NN + SCAN_ELEMS - 1) / SCAN_ELEMS)   // 98

// ---------------------------------------------------------------------------
// int degree counts: cntO[src[e]]++, cntI[dst[e]]++
__global__ __launch_bounds__(256) void count_kernel(
    const int* __restrict__ src, const int* __restrict__ dst,
    int* __restrict__ cntO, int* __restrict__ cntI, int n)
{
    int i = blockIdx.x * 256 + threadIdx.x;
    if (i < n) {
        atomicAdd(&cntO[src[i]], 1);
        atomicAdd(&cntI[dst[i]], 1);
    }
}

// degO (in place int->float rsqrt), degI = rsqrt(max(cntI,1))
__global__ __launch_bounds__(256) void rsqrt_conv(
    int* __restrict__ cntO, const int* __restrict__ cntI,
    float* __restrict__ degI, int n)
{
    int i = blockIdx.x * 256 + threadIdx.x;
    if (i < n) {
        int c = cntO[i];
        reinterpret_cast<float*>(cntO)[i] = rsqrtf(fmaxf((float)c, 1.0f));
        degI[i] = rsqrtf(fmaxf((float)cntI[i], 1.0f));
    }
}

// ---------------------------------------------------------------------------
// 3-kernel exclusive scan of cntI -> row_ptr (SCAN_ELEMS per block)
__global__ __launch_bounds__(256) void scanA(const int* __restrict__ cnt,
                                             int* __restrict__ bsum, int n)
{
    __shared__ int s[256];
    const int t = threadIdx.x, b = blockIdx.x;
    const int base = b * SCAN_ELEMS + t * 4;
    int v = 0;
    #pragma unroll
    for (int k = 0; k < 4; ++k) { int i = base + k; if (i < n) v += cnt[i]; }
    s[t] = v; __syncthreads();
    for (int off = 128; off > 0; off >>= 1) {
        if (t < off) s[t] += s[t + off];
        __syncthreads();
    }
    if (t == 0) bsum[b] = s[0];
}

__global__ void scanB(int* __restrict__ bsum, int nb,
                      int* __restrict__ row_ptr_end, int total)
{
    if (threadIdx.x == 0 && blockIdx.x == 0) {
        int run = 0;
        for (int i = 0; i < nb; ++i) { int v = bsum[i]; bsum[i] = run; run += v; }
        *row_ptr_end = total;   // row_ptr[NN] = NE
    }
}

__global__ __launch_bounds__(256) void scanC(const int* __restrict__ cnt,
                                             const int* __restrict__ bsum,
                                             int* __restrict__ row_ptr, int n)
{
    __shared__ int s[256];
    const int t = threadIdx.x, b = blockIdx.x;
    const int base = b * SCAN_ELEMS + t * 4;
    int loc[4]; int v = 0;
    #pragma unroll
    for (int k = 0; k < 4; ++k) {
        int i = base + k;
        loc[k] = (i < n) ? cnt[i] : 0;
        v += loc[k];
    }
    s[t] = v; __syncthreads();
    // Hillis-Steele inclusive scan over thread sums
    for (int off = 1; off < 256; off <<= 1) {
        int x = (t >= off) ? s[t - off] : 0;
        __syncthreads();
        s[t] += x;
        __syncthreads();
    }
    int excl = bsum[b] + ((t > 0) ? s[t - 1] : 0);
    #pragma unroll
    for (int k = 0; k < 4; ++k) {
        int i = base + k;
        if (i < n) { row_ptr[i] = excl; excl += loc[k]; }
    }
}

// fill csr_src: consumes cntI (decrements to 0)
__global__ __launch_bounds__(256) void csr_scatter(
    const int* __restrict__ src, const int* __restrict__ dst,
    const int* __restrict__ row_ptr, int* __restrict__ cntI,
    int* __restrict__ csr_src, int n)
{
    int e = blockIdx.x * 256 + threadIdx.x;
    if (e < n) {
        int d = dst[e];
        int pos = row_ptr[d] + atomicSub(&cntI[d], 1) - 1;
        csr_src[pos] = src[e];
    }
}

// ---------------------------------------------------------------------------
// H[i,j] = scale[i] * sum_k X[i,k] * W[k,j]     (K = 128 fixed)
template<int NOUT>
__global__ __launch_bounds__(256) void gemm_scale(
    const float* __restrict__ X,     // [N, 128]
    const float* __restrict__ W,     // [128, NOUT]
    const float* __restrict__ scale, // [N]  (deg_out^-1/2)
    float* __restrict__ H,           // [N, NOUT]
    int nrows)
{
    constexpr int K = KF;
    constexpr int ROWS = 16;
    __shared__ float Wl[K * NOUT];
    __shared__ float Xs[ROWS * K];

    const int tid = threadIdx.x;
    for (int i = tid; i < K * NOUT; i += 256) Wl[i] = W[i];

    const int row0 = blockIdx.x * ROWS;
    const float4* X4 = reinterpret_cast<const float4*>(X + (size_t)row0 * K);
    float4* Xs4 = reinterpret_cast<float4*>(Xs);
    #pragma unroll
    for (int i = tid; i < ROWS * K / 4; i += 256) Xs4[i] = X4[i];
    __syncthreads();

    constexpr int RPP = 256 / NOUT;
    constexpr int NACC = ROWS / RPP;
    const int j  = tid % NOUT;
    const int r0 = tid / NOUT;

    float acc[NACC];
    #pragma unroll
    for (int a = 0; a < NACC; ++a) acc[a] = 0.0f;

    #pragma unroll 4
    for (int k = 0; k < K; ++k) {
        float w = Wl[k * NOUT + j];
        #pragma unroll
        for (int a = 0; a < NACC; ++a)
            acc[a] += Xs[(r0 + a * RPP) * K + k] * w;
    }

    #pragma unroll
    for (int a = 0; a < NACC; ++a) {
        int r = row0 + r0 + a * RPP;
        if (r < nrows)
            H[(size_t)r * NOUT + j] = acc[a] * scale[r];
    }
}

// ---------------------------------------------------------------------------
// pull aggregation, 128 feats: one wave per node, lane owns float2.
// out[d,:] = (sum_{s in N(d)} H[s,:]) * degI[d] + b  (+relu)
template<bool RELU>
__global__ __launch_bounds__(256) void pull128(
    const float* __restrict__ H, const int* __restrict__ row_ptr,
    const int* __restrict__ csr, const float* __restrict__ degI,
    const float* __restrict__ b, float* __restrict__ out)
{
    const int node = blockIdx.x * 4 + (threadIdx.x >> 6);
    if (node >= NN) return;
    const int lane = threadIdx.x & 63;
    const int beg = row_ptr[node], end = row_ptr[node + 1];
    const float2* __restrict__ H2 = reinterpret_cast<const float2*>(H);
    float ax = 0.0f, ay = 0.0f;
    int j = beg;
    for (; j + 3 < end; j += 4) {
        int s0 = csr[j], s1 = csr[j + 1], s2 = csr[j + 2], s3 = csr[j + 3];
        float2 v0 = H2[(size_t)s0 * 64 + lane];
        float2 v1 = H2[(size_t)s1 * 64 + lane];
        float2 v2 = H2[(size_t)s2 * 64 + lane];
        float2 v3 = H2[(size_t)s3 * 64 + lane];
        ax += v0.x + v1.x + v2.x + v3.x;
        ay += v0.y + v1.y + v2.y + v3.y;
    }
    for (; j < end; ++j) {
        float2 v = H2[(size_t)csr[j] * 64 + lane];
        ax += v.x; ay += v.y;
    }
    const float sc = degI[node];
    const float2 bb = reinterpret_cast<const float2*>(b)[lane];
    float ox = ax * sc + bb.x, oy = ay * sc + bb.y;
    if (RELU) { ox = fmaxf(ox, 0.0f); oy = fmaxf(oy, 0.0f); }
    reinterpret_cast<float2*>(out)[(size_t)node * 64 + lane] = make_float2(ox, oy);
}

// pull aggregation, 64 feats: one wave per node, lane owns 1 float.
template<bool RELU>
__global__ __launch_bounds__(256) void pull64(
    const float* __restrict__ H, const int* __restrict__ row_ptr,
    const int* __restrict__ csr, const float* __restrict__ degI,
    const float* __restrict__ b, float* __restrict__ out)
{
    const int node = blockIdx.x * 4 + (threadIdx.x >> 6);
    if (node >= NN) return;
    const int lane = threadIdx.x & 63;
    const int beg = row_ptr[node], end = row_ptr[node + 1];
    float acc = 0.0f;
    int j = beg;
    for (; j + 3 < end; j += 4) {
        int s0 = csr[j], s1 = csr[j + 1], s2 = csr[j + 2], s3 = csr[j + 3];
        acc += H[(size_t)s0 * 64 + lane] + H[(size_t)s1 * 64 + lane]
             + H[(size_t)s2 * 64 + lane] + H[(size_t)s3 * 64 + lane];
    }
    for (; j < end; ++j) acc += H[(size_t)csr[j] * 64 + lane];
    float o = acc * degI[node] + b[lane];
    if (RELU) o = fmaxf(o, 0.0f);
    out[(size_t)node * 64 + lane] = o;
}

// ---------------------------------------------------------------------------
extern "C" void kernel_launch(void* const* d_in, const int* in_sizes, int n_in,
                              void* d_out, int out_size, void* d_ws, size_t ws_size,
                              hipStream_t stream)
{
    const float* x   = (const float*)d_in[0];
    const int*   src = (const int*)d_in[1];
    const int*   dst = (const int*)d_in[2];
    const float* W1  = (const float*)d_in[3];
    const float* b1  = (const float*)d_in[4];
    const float* W2  = (const float*)d_in[5];
    const float* b2  = (const float*)d_in[6];
    float* out = (float*)d_out;

    // workspace layout (4B elements)
    char* wsb = (char*)d_ws;
    int*   degO_i  = (int*)wsb;                          // counts -> in-place float rsqrt
    int*   cntI    = degO_i + 100352;                    // consumed by csr_scatter
    float* degI    = (float*)(cntI + 100352);
    int*   row_ptr = (int*)(degI + 100352);              // NN+1 entries
    int*   bsum    = row_ptr + 100352;
    int*   csr     = bsum + 1024;                        // 1.6M
    float* h1      = (float*)(csr + 1600512);            // [NN,128]; reused as h2
    float* agg1    = h1 + (size_t)NN * F1;               // [NN,128]
    const float* degO = (const float*)degO_i;

    // zero only the count arrays (harness poisons ws with 0xAA)
    hipMemsetAsync(degO_i, 0, 2 * 100352 * sizeof(int), stream);

    // ---- graph preprocessing: degrees + CSR by dst ----
    count_kernel<<<(NE + 255) / 256, 256, 0, stream>>>(src, dst, degO_i, cntI, NE);
    scanA<<<SCAN_NB, 256, 0, stream>>>(cntI, bsum, NN);
    scanB<<<1, 64, 0, stream>>>(bsum, SCAN_NB, row_ptr + NN, NE);
    scanC<<<SCAN_NB, 256, 0, stream>>>(cntI, bsum, row_ptr, NN);
    rsqrt_conv<<<(NN + 255) / 256, 256, 0, stream>>>(degO_i, cntI, degI, NN);
    csr_scatter<<<(NE + 255) / 256, 256, 0, stream>>>(src, dst, row_ptr, cntI, csr, NE);

    // ---- layer 1: h1 = (x @ W1) * degO ; agg1 = relu(pull(h1) * degI + b1) ----
    gemm_scale<F1><<<NN / 16, 256, 0, stream>>>(x, W1, degO, h1, NN);
    pull128<true><<<(NN + 3) / 4, 256, 0, stream>>>(h1, row_ptr, csr, degI, b1, agg1);

    // ---- layer 2: h2 = (agg1 @ W2) * degO ; out = pull(h2) * degI + b2 ----
    gemm_scale<F2><<<NN / 16, 256, 0, stream>>>(agg1, W2, degO, h1, NN);
    pull64<false><<<(NN + 3) / 4, 256, 0, stream>>>(h1, row_ptr, csr, degI, b2, out);
}

// Round 7
// 647.130 us; speedup vs baseline: 6.9571x; 1.0823x over previous
//
#include <hip/hip_runtime.h>
#include <hip/hip_bf16.h>

// Problem constants (from reference)
#define NN 100000      // nodes
#define NE 1600000     // edges
#define KF 128         // in feats == hidden
#define F1 128         // layer-1 out feats
#define F2 64          // layer-2 out feats

#define SCAN_ELEMS 1024
#define SCAN_NB ((NN + SCAN_ELEMS - 1) / SCAN_ELEMS)   // 98

// ---------------------------------------------------------------------------
// degree counts, 4 edges per thread (int4 loads, 8 independent atomic chains)
__global__ __launch_bounds__(256) void count4(
    const int4* __restrict__ src4, const int4* __restrict__ dst4,
    int* __restrict__ cntO, int* __restrict__ cntI, int n4)
{
    int i = blockIdx.x * 256 + threadIdx.x;
    if (i < n4) {
        int4 s = src4[i]; int4 d = dst4[i];
        atomicAdd(&cntO[s.x], 1); atomicAdd(&cntO[s.y], 1);
        atomicAdd(&cntO[s.z], 1); atomicAdd(&cntO[s.w], 1);
        atomicAdd(&cntI[d.x], 1); atomicAdd(&cntI[d.y], 1);
        atomicAdd(&cntI[d.z], 1); atomicAdd(&cntI[d.w], 1);
    }
}

// degO (in-place int->float rsqrt), degI = rsqrt(max(cntI,1)), cursor = row_ptr[i+1]
__global__ __launch_bounds__(256) void rsqrt_conv(
    int* __restrict__ cntO, const int* __restrict__ cntI,
    float* __restrict__ degI, const int* __restrict__ row_ptr,
    int* __restrict__ cursor, int n)
{
    int i = blockIdx.x * 256 + threadIdx.x;
    if (i < n) {
        int c = cntO[i];
        reinterpret_cast<float*>(cntO)[i] = rsqrtf(fmaxf((float)c, 1.0f));
        degI[i] = rsqrtf(fmaxf((float)cntI[i], 1.0f));
        cursor[i] = row_ptr[i + 1];
    }
}

// ---------------------------------------------------------------------------
// 3-kernel exclusive scan of cntI -> row_ptr
__global__ __launch_bounds__(256) void scanA(const int* __restrict__ cnt,
                                             int* __restrict__ bsum, int n)
{
    __shared__ int s[256];
    const int t = threadIdx.x, b = blockIdx.x;
    const int base = b * SCAN_ELEMS + t * 4;
    int v = 0;
    #pragma unroll
    for (int k = 0; k < 4; ++k) { int i = base + k; if (i < n) v += cnt[i]; }
    s[t] = v; __syncthreads();
    for (int off = 128; off > 0; off >>= 1) {
        if (t < off) s[t] += s[t + off];
        __syncthreads();
    }
    if (t == 0) bsum[b] = s[0];
}

__global__ void scanB(int* __restrict__ bsum, int nb,
                      int* __restrict__ row_ptr_end, int total)
{
    if (threadIdx.x == 0 && blockIdx.x == 0) {
        int run = 0;
        for (int i = 0; i < nb; ++i) { int v = bsum[i]; bsum[i] = run; run += v; }
        *row_ptr_end = total;   // row_ptr[NN] = NE
    }
}

__global__ __launch_bounds__(256) void scanC(const int* __restrict__ cnt,
                                             const int* __restrict__ bsum,
                                             int* __restrict__ row_ptr, int n)
{
    __shared__ int s[256];
    const int t = threadIdx.x, b = blockIdx.x;
    const int base = b * SCAN_ELEMS + t * 4;
    int loc[4]; int v = 0;
    #pragma unroll
    for (int k = 0; k < 4; ++k) {
        int i = base + k;
        loc[k] = (i < n) ? cnt[i] : 0;
        v += loc[k];
    }
    s[t] = v; __syncthreads();
    for (int off = 1; off < 256; off <<= 1) {
        int x = (t >= off) ? s[t - off] : 0;
        __syncthreads();
        s[t] += x;
        __syncthreads();
    }
    int excl = bsum[b] + ((t > 0) ? s[t - 1] : 0);
    #pragma unroll
    for (int k = 0; k < 4; ++k) {
        int i = base + k;
        if (i < n) { row_ptr[i] = excl; excl += loc[k]; }
    }
}

// fill csr_src: single atomic per edge on cursor (= row_ptr[i+1] copy), 4 edges/thread
__global__ __launch_bounds__(256) void csr_scatter4(
    const int4* __restrict__ src4, const int4* __restrict__ dst4,
    int* __restrict__ cursor, int* __restrict__ csr_src, int n4)
{
    int i = blockIdx.x * 256 + threadIdx.x;
    if (i < n4) {
        int4 s = src4[i]; int4 d = dst4[i];
        int p0 = atomicSub(&cursor[d.x], 1) - 1;
        int p1 = atomicSub(&cursor[d.y], 1) - 1;
        int p2 = atomicSub(&cursor[d.z], 1) - 1;
        int p3 = atomicSub(&cursor[d.w], 1) - 1;
        csr_src[p0] = s.x; csr_src[p1] = s.y;
        csr_src[p2] = s.z; csr_src[p3] = s.w;
    }
}

// ---------------------------------------------------------------------------
// Register-tiled GEMM: H[i,j] = scale[i] * sum_k X[i,k]*W[k,j], K=128.
// 256 threads; thread tile TM=4 rows x TN=8 cols; K chunked at 32, dbuf LDS.
template<int NOUT>
__global__ __launch_bounds__(256) void gemm_rt(
    const float* __restrict__ X, const float* __restrict__ W,
    const float* __restrict__ scale, float* __restrict__ H, int nrows)
{
    constexpr int K = KF, KC = 32, TN = 8, TM = 4;
    constexpr int CG = NOUT / TN;        // col groups: 16 / 8
    constexpr int RG = 256 / CG;         // row groups: 16 / 32
    constexpr int BM = RG * TM;          // block rows: 64 / 128
    constexpr int XP = KC + 4;           // padded Xs stride (36 floats, 16B-aligned)

    __shared__ float Xs[2][BM][XP];
    __shared__ float Ws[2][KC][NOUT];

    const int t = threadIdx.x;
    const int cg = t % CG, rg = t / CG;
    const int row0 = blockIdx.x * BM;

    constexpr int XL = BM * (KC / 4) / 256;   // float4 X-loads per thread: 2 / 4
    constexpr int WL = KC * (NOUT / 4) / 256; // float4 W-loads per thread: 4 / 2

    float acc[TM][TN];
    #pragma unroll
    for (int i = 0; i < TM; ++i)
        #pragma unroll
        for (int j = 0; j < TN; ++j) acc[i][j] = 0.0f;

    auto load_chunk = [&](int buf, int kc) {
        #pragma unroll
        for (int j = 0; j < XL; ++j) {
            int idx = t + j * 256;                 // float4 index in BM x KC tile
            int r = idx >> 3, kq = idx & 7;        // 8 float4 per row
            int gr = min(row0 + r, nrows - 1);
            float4 v = reinterpret_cast<const float4*>(X + (size_t)gr * K + kc)[kq];
            *reinterpret_cast<float4*>(&Xs[buf][r][kq * 4]) = v;
        }
        #pragma unroll
        for (int j = 0; j < WL; ++j) {
            int idx = t + j * 256;                 // float4 index in KC x NOUT tile
            int kr = idx / (NOUT / 4), c4 = idx % (NOUT / 4);
            float4 v = reinterpret_cast<const float4*>(W + (size_t)(kc + kr) * NOUT)[c4];
            *reinterpret_cast<float4*>(&Ws[buf][kr][c4 * 4]) = v;
        }
    };

    load_chunk(0, 0);
    int buf = 0;
    for (int kc = 0; kc < K; kc += KC) {
        __syncthreads();
        if (kc + KC < K) load_chunk(buf ^ 1, kc + KC);
        #pragma unroll
        for (int k = 0; k < KC; ++k) {
            float w[TN], a[TM];
            *reinterpret_cast<float4*>(&w[0]) =
                *reinterpret_cast<const float4*>(&Ws[buf][k][cg * TN]);
            *reinterpret_cast<float4*>(&w[4]) =
                *reinterpret_cast<const float4*>(&Ws[buf][k][cg * TN + 4]);
            #pragma unroll
            for (int i = 0; i < TM; ++i) a[i] = Xs[buf][rg * TM + i][k];
            #pragma unroll
            for (int i = 0; i < TM; ++i)
                #pragma unroll
                for (int j = 0; j < TN; ++j)
                    acc[i][j] += a[i] * w[j];
        }
        buf ^= 1;
    }

    #pragma unroll
    for (int i = 0; i < TM; ++i) {
        int r = row0 + rg * TM + i;
        if (r < nrows) {
            float s = scale[r];
            float4 o0, o1;
            o0.x = acc[i][0] * s; o0.y = acc[i][1] * s;
            o0.z = acc[i][2] * s; o0.w = acc[i][3] * s;
            o1.x = acc[i][4] * s; o1.y = acc[i][5] * s;
            o1.z = acc[i][6] * s; o1.w = acc[i][7] * s;
            float4* dst = reinterpret_cast<float4*>(H + (size_t)r * NOUT + cg * TN);
            dst[0] = o0; dst[1] = o1;
        }
    }
}

// ---------------------------------------------------------------------------
// pull aggregation, 128 feats: one wave per node, lane owns float2.
template<bool RELU>
__global__ __launch_bounds__(256) void pull128(
    const float* __restrict__ H, const int* __restrict__ row_ptr,
    const int* __restrict__ csr, const float* __restrict__ degI,
    const float* __restrict__ b, float* __restrict__ out)
{
    const int node = blockIdx.x * 4 + (threadIdx.x >> 6);
    if (node >= NN) return;
    const int lane = threadIdx.x & 63;
    const int beg = row_ptr[node], end = row_ptr[node + 1];
    const float2* __restrict__ H2 = reinterpret_cast<const float2*>(H);
    float ax = 0.0f, ay = 0.0f;
    int j = beg;
    for (; j + 3 < end; j += 4) {
        int s0 = csr[j], s1 = csr[j + 1], s2 = csr[j + 2], s3 = csr[j + 3];
        float2 v0 = H2[(size_t)s0 * 64 + lane];
        float2 v1 = H2[(size_t)s1 * 64 + lane];
        float2 v2 = H2[(size_t)s2 * 64 + lane];
        float2 v3 = H2[(size_t)s3 * 64 + lane];
        ax += v0.x + v1.x + v2.x + v3.x;
        ay += v0.y + v1.y + v2.y + v3.y;
    }
    for (; j < end; ++j) {
        float2 v = H2[(size_t)csr[j] * 64 + lane];
        ax += v.x; ay += v.y;
    }
    const float sc = degI[node];
    const float2 bb = reinterpret_cast<const float2*>(b)[lane];
    float ox = ax * sc + bb.x, oy = ay * sc + bb.y;
    if (RELU) { ox = fmaxf(ox, 0.0f); oy = fmaxf(oy, 0.0f); }
    reinterpret_cast<float2*>(out)[(size_t)node * 64 + lane] = make_float2(ox, oy);
}

// pull aggregation, 64 feats: one wave per node, lane owns 1 float.
template<bool RELU>
__global__ __launch_bounds__(256) void pull64(
    const float* __restrict__ H, const int* __restrict__ row_ptr,
    const int* __restrict__ csr, const float* __restrict__ degI,
    const float* __restrict__ b, float* __restrict__ out)
{
    const int node = blockIdx.x * 4 + (threadIdx.x >> 6);
    if (node >= NN) return;
    const int lane = threadIdx.x & 63;
    const int beg = row_ptr[node], end = row_ptr[node + 1];
    float acc = 0.0f;
    int j = beg;
    for (; j + 3 < end; j += 4) {
        int s0 = csr[j], s1 = csr[j + 1], s2 = csr[j + 2], s3 = csr[j + 3];
        acc += H[(size_t)s0 * 64 + lane] + H[(size_t)s1 * 64 + lane]
             + H[(size_t)s2 * 64 + lane] + H[(size_t)s3 * 64 + lane];
    }
    for (; j < end; ++j) acc += H[(size_t)csr[j] * 64 + lane];
    float o = acc * degI[node] + b[lane];
    if (RELU) o = fmaxf(o, 0.0f);
    out[(size_t)node * 64 + lane] = o;
}

// ---------------------------------------------------------------------------
extern "C" void kernel_launch(void* const* d_in, const int* in_sizes, int n_in,
                              void* d_out, int out_size, void* d_ws, size_t ws_size,
                              hipStream_t stream)
{
    const float* x   = (const float*)d_in[0];
    const int*   src = (const int*)d_in[1];
    const int*   dst = (const int*)d_in[2];
    const float* W1  = (const float*)d_in[3];
    const float* b1  = (const float*)d_in[4];
    const float* W2  = (const float*)d_in[5];
    const float* b2  = (const float*)d_in[6];
    float* out = (float*)d_out;

    // workspace layout (4B elements)
    char* wsb = (char*)d_ws;
    int*   degO_i  = (int*)wsb;                 // counts -> in-place float rsqrt
    int*   cntI    = degO_i + 100352;
    float* degI    = (float*)(cntI + 100352);
    int*   row_ptr = (int*)(degI + 100352);     // NN+1 entries
    int*   cursor  = row_ptr + 100352;          // CSR fill cursors
    int*   bsum    = cursor + 100352;
    int*   csr     = bsum + 1024;               // 1.6M
    float* h1      = (float*)(csr + 1600512);   // [NN,128]; reused as h2
    float* agg1    = h1 + (size_t)NN * F1;      // [NN,128]
    const float* degO = (const float*)degO_i;

    hipMemsetAsync(degO_i, 0, 2 * 100352 * sizeof(int), stream);

    // ---- graph preprocessing: degrees + CSR by dst ----
    count4<<<(NE / 4 + 255) / 256, 256, 0, stream>>>(
        (const int4*)src, (const int4*)dst, degO_i, cntI, NE / 4);
    scanA<<<SCAN_NB, 256, 0, stream>>>(cntI, bsum, NN);
    scanB<<<1, 64, 0, stream>>>(bsum, SCAN_NB, row_ptr + NN, NE);
    scanC<<<SCAN_NB, 256, 0, stream>>>(cntI, bsum, row_ptr, NN);
    rsqrt_conv<<<(NN + 255) / 256, 256, 0, stream>>>(degO_i, cntI, degI,
                                                     row_ptr, cursor, NN);
    csr_scatter4<<<(NE / 4 + 255) / 256, 256, 0, stream>>>(
        (const int4*)src, (const int4*)dst, cursor, csr, NE / 4);

    // ---- layer 1 ----
    gemm_rt<F1><<<(NN + 63) / 64, 256, 0, stream>>>(x, W1, degO, h1, NN);
    pull128<true><<<(NN + 3) / 4, 256, 0, stream>>>(h1, row_ptr, csr, degI, b1, agg1);

    // ---- layer 2 ----
    gemm_rt<F2><<<(NN + 127) / 128, 256, 0, stream>>>(agg1, W2, degO, h1, NN);
    pull64<false><<<(NN + 3) / 4, 256, 0, stream>>>(h1, row_ptr, csr, degI, b2, out);
}

// Round 8
// 496.207 us; speedup vs baseline: 9.0732x; 1.3042x over previous
//
#include <hip/hip_runtime.h>
#include <hip/hip_bf16.h>

// Problem constants (from reference)
#define NN 100000      // nodes
#define NE 1600000     // edges
#define KF 128         // in feats == hidden
#define F1 128         // layer-1 out feats
#define F2 64          // layer-2 out feats

#define BSHIFT 8                        // 256 nodes per bucket
#define NBKT ((NN + 255) >> BSHIFT)     // 391 buckets
#define EPB 2048                        // edges per block, phases A/C
#define N4 (NE / 4)                     // 400000 int4 edge-packs

// ---------------------------------------------------------------------------
// Phase A: LDS bucket histogram (by dst>>8) + fused src out-degree count
__global__ __launch_bounds__(256) void bkt_hist(
    const int4* __restrict__ src4, const int4* __restrict__ dst4,
    int* __restrict__ cntO, int* __restrict__ bktCnt)
{
    __shared__ int h[512];
    const int t = threadIdx.x;
    for (int i = t; i < 512; i += 256) h[i] = 0;
    __syncthreads();
    #pragma unroll
    for (int r = 0; r < EPB / 4 / 256; ++r) {           // 2 iters
        int i = blockIdx.x * (EPB / 4) + r * 256 + t;
        if (i < N4) {
            int4 s = src4[i]; int4 d = dst4[i];
            atomicAdd(&cntO[s.x], 1); atomicAdd(&cntO[s.y], 1);
            atomicAdd(&cntO[s.z], 1); atomicAdd(&cntO[s.w], 1);
            atomicAdd(&h[d.x >> BSHIFT], 1); atomicAdd(&h[d.y >> BSHIFT], 1);
            atomicAdd(&h[d.z >> BSHIFT], 1); atomicAdd(&h[d.w >> BSHIFT], 1);
        }
    }
    __syncthreads();
    for (int i = t; i < 512; i += 256)
        if (h[i]) atomicAdd(&bktCnt[i], h[i]);
}

// Phase B: exclusive scan of 512 bucket counts -> bases + cursors; row_ptr[NN]=NE
__global__ __launch_bounds__(512) void bkt_scan(
    const int* __restrict__ bktCnt, int* __restrict__ bktBase,
    int* __restrict__ bktCur, int* __restrict__ row_ptr_end)
{
    __shared__ int s[512];
    const int t = threadIdx.x;
    int v = bktCnt[t];
    s[t] = v; __syncthreads();
    for (int off = 1; off < 512; off <<= 1) {
        int x = (t >= off) ? s[t - off] : 0;
        __syncthreads();
        s[t] += x;
        __syncthreads();
    }
    int excl = s[t] - v;
    bktBase[t] = excl;
    bktCur[t] = excl;
    if (t == 511) { bktBase[512] = s[511]; *row_ptr_end = s[511]; }  // == NE
}

// degO: in-place int count -> rsqrt(max(c,1))
__global__ __launch_bounds__(256) void rsqrtO(int* __restrict__ cntO, int n)
{
    int i = blockIdx.x * 256 + threadIdx.x;
    if (i < n) {
        int c = cntO[i];
        reinterpret_cast<float*>(cntO)[i] = rsqrtf(fmaxf((float)c, 1.0f));
    }
}

// Phase C: scatter edges into bucket-contiguous ebuf as (dst, src)
__global__ __launch_bounds__(256) void bkt_scatter(
    const int4* __restrict__ src4, const int4* __restrict__ dst4,
    int* __restrict__ bktCur, int2* __restrict__ ebuf)
{
    __shared__ int h[512], bb[512], cur[512];
    const int t = threadIdx.x;
    for (int i = t; i < 512; i += 256) h[i] = 0;
    __syncthreads();
    #pragma unroll
    for (int r = 0; r < EPB / 4 / 256; ++r) {
        int i = blockIdx.x * (EPB / 4) + r * 256 + t;
        if (i < N4) {
            int4 d = dst4[i];
            atomicAdd(&h[d.x >> BSHIFT], 1); atomicAdd(&h[d.y >> BSHIFT], 1);
            atomicAdd(&h[d.z >> BSHIFT], 1); atomicAdd(&h[d.w >> BSHIFT], 1);
        }
    }
    __syncthreads();
    for (int i = t; i < 512; i += 256) {
        bb[i] = h[i] ? atomicAdd(&bktCur[i], h[i]) : 0;
        cur[i] = 0;
    }
    __syncthreads();
    #pragma unroll
    for (int r = 0; r < EPB / 4 / 256; ++r) {
        int i = blockIdx.x * (EPB / 4) + r * 256 + t;
        if (i < N4) {
            int4 s = src4[i]; int4 d = dst4[i];
            int b0 = d.x >> BSHIFT, b1 = d.y >> BSHIFT;
            int b2 = d.z >> BSHIFT, b3 = d.w >> BSHIFT;
            int l0 = atomicAdd(&cur[b0], 1);
            int l1 = atomicAdd(&cur[b1], 1);
            int l2 = atomicAdd(&cur[b2], 1);
            int l3 = atomicAdd(&cur[b3], 1);
            ebuf[bb[b0] + l0] = make_int2(d.x, s.x);
            ebuf[bb[b1] + l1] = make_int2(d.y, s.y);
            ebuf[bb[b2] + l2] = make_int2(d.z, s.z);
            ebuf[bb[b3] + l3] = make_int2(d.w, s.w);
        }
    }
}

// Phase D: per-bucket local CSR via LDS count/scan/cursor; writes row_ptr, degI, csr
__global__ __launch_bounds__(256) void bkt_csr(
    const int2* __restrict__ ebuf, const int* __restrict__ bktBase,
    int* __restrict__ row_ptr, float* __restrict__ degI, int* __restrict__ csr)
{
    const int b = blockIdx.x;               // 0..NBKT-1
    const int node0 = b << BSHIFT;
    const int ebase = bktBase[b];
    const int ecnt  = bktBase[b + 1] - ebase;
    __shared__ int cnt[256], sc[256], cur[256];
    const int t = threadIdx.x;
    cnt[t] = 0; __syncthreads();
    for (int i = t; i < ecnt; i += 256)
        atomicAdd(&cnt[ebuf[ebase + i].x - node0], 1);
    __syncthreads();
    int v = cnt[t];
    sc[t] = v; __syncthreads();
    for (int off = 1; off < 256; off <<= 1) {
        int x = (t >= off) ? sc[t - off] : 0;
        __syncthreads();
        sc[t] += x;
        __syncthreads();
    }
    int excl = sc[t] - v;
    int node = node0 + t;
    if (node < NN) {
        row_ptr[node] = ebase + excl;
        degI[node] = rsqrtf(fmaxf((float)v, 1.0f));
    }
    cur[t] = excl; __syncthreads();
    for (int i = t; i < ecnt; i += 256) {
        int2 e = ebuf[ebase + i];
        int slot = atomicAdd(&cur[e.x - node0], 1);
        csr[ebase + slot] = e.y;
    }
}

// ---------------------------------------------------------------------------
// Register-tiled GEMM: H[i,j] = scale[i] * sum_k X[i,k]*W[k,j], K=128.
template<int NOUT>
__global__ __launch_bounds__(256) void gemm_rt(
    const float* __restrict__ X, const float* __restrict__ W,
    const float* __restrict__ scale, float* __restrict__ H, int nrows)
{
    constexpr int K = KF, KC = 32, TN = 8, TM = 4;
    constexpr int CG = NOUT / TN;
    constexpr int RG = 256 / CG;
    constexpr int BM = RG * TM;
    constexpr int XP = KC + 4;

    __shared__ float Xs[2][BM][XP];
    __shared__ float Ws[2][KC][NOUT];

    const int t = threadIdx.x;
    const int cg = t % CG, rg = t / CG;
    const int row0 = blockIdx.x * BM;

    constexpr int XL = BM * (KC / 4) / 256;
    constexpr int WL = KC * (NOUT / 4) / 256;

    float acc[TM][TN];
    #pragma unroll
    for (int i = 0; i < TM; ++i)
        #pragma unroll
        for (int j = 0; j < TN; ++j) acc[i][j] = 0.0f;

    auto load_chunk = [&](int buf, int kc) {
        #pragma unroll
        for (int j = 0; j < XL; ++j) {
            int idx = t + j * 256;
            int r = idx >> 3, kq = idx & 7;
            int gr = min(row0 + r, nrows - 1);
            float4 v = reinterpret_cast<const float4*>(X + (size_t)gr * K + kc)[kq];
            *reinterpret_cast<float4*>(&Xs[buf][r][kq * 4]) = v;
        }
        #pragma unroll
        for (int j = 0; j < WL; ++j) {
            int idx = t + j * 256;
            int kr = idx / (NOUT / 4), c4 = idx % (NOUT / 4);
            float4 v = reinterpret_cast<const float4*>(W + (size_t)(kc + kr) * NOUT)[c4];
            *reinterpret_cast<float4*>(&Ws[buf][kr][c4 * 4]) = v;
        }
    };

    load_chunk(0, 0);
    int buf = 0;
    for (int kc = 0; kc < K; kc += KC) {
        __syncthreads();
        if (kc + KC < K) load_chunk(buf ^ 1, kc + KC);
        #pragma unroll
        for (int k = 0; k < KC; ++k) {
            float w[TN], a[TM];
            *reinterpret_cast<float4*>(&w[0]) =
                *reinterpret_cast<const float4*>(&Ws[buf][k][cg * TN]);
            *reinterpret_cast<float4*>(&w[4]) =
                *reinterpret_cast<const float4*>(&Ws[buf][k][cg * TN + 4]);
            #pragma unroll
            for (int i = 0; i < TM; ++i) a[i] = Xs[buf][rg * TM + i][k];
            #pragma unroll
            for (int i = 0; i < TM; ++i)
                #pragma unroll
                for (int j = 0; j < TN; ++j)
                    acc[i][j] += a[i] * w[j];
        }
        buf ^= 1;
    }

    #pragma unroll
    for (int i = 0; i < TM; ++i) {
        int r = row0 + rg * TM + i;
        if (r < nrows) {
            float s = scale[r];
            float4 o0, o1;
            o0.x = acc[i][0] * s; o0.y = acc[i][1] * s;
            o0.z = acc[i][2] * s; o0.w = acc[i][3] * s;
            o1.x = acc[i][4] * s; o1.y = acc[i][5] * s;
            o1.z = acc[i][6] * s; o1.w = acc[i][7] * s;
            float4* dst = reinterpret_cast<float4*>(H + (size_t)r * NOUT + cg * TN);
            dst[0] = o0; dst[1] = o1;
        }
    }
}

// ---------------------------------------------------------------------------
// pull aggregation, 128 feats: one wave per node, lane owns float2.
template<bool RELU>
__global__ __launch_bounds__(256) void pull128(
    const float* __restrict__ H, const int* __restrict__ row_ptr,
    const int* __restrict__ csr, const float* __restrict__ degI,
    const float* __restrict__ b, float* __restrict__ out)
{
    const int node = blockIdx.x * 4 + (threadIdx.x >> 6);
    if (node >= NN) return;
    const int lane = threadIdx.x & 63;
    const int beg = row_ptr[node], end = row_ptr[node + 1];
    const float2* __restrict__ H2 = reinterpret_cast<const float2*>(H);
    float ax = 0.0f, ay = 0.0f;
    int j = beg;
    for (; j + 3 < end; j += 4) {
        int s0 = csr[j], s1 = csr[j + 1], s2 = csr[j + 2], s3 = csr[j + 3];
        float2 v0 = H2[(size_t)s0 * 64 + lane];
        float2 v1 = H2[(size_t)s1 * 64 + lane];
        float2 v2 = H2[(size_t)s2 * 64 + lane];
        float2 v3 = H2[(size_t)s3 * 64 + lane];
        ax += v0.x + v1.x + v2.x + v3.x;
        ay += v0.y + v1.y + v2.y + v3.y;
    }
    for (; j < end; ++j) {
        float2 v = H2[(size_t)csr[j] * 64 + lane];
        ax += v.x; ay += v.y;
    }
    const float sc = degI[node];
    const float2 bb = reinterpret_cast<const float2*>(b)[lane];
    float ox = ax * sc + bb.x, oy = ay * sc + bb.y;
    if (RELU) { ox = fmaxf(ox, 0.0f); oy = fmaxf(oy, 0.0f); }
    reinterpret_cast<float2*>(out)[(size_t)node * 64 + lane] = make_float2(ox, oy);
}

// pull aggregation, 64 feats: one wave per node, lane owns 1 float.
template<bool RELU>
__global__ __launch_bounds__(256) void pull64(
    const float* __restrict__ H, const int* __restrict__ row_ptr,
    const int* __restrict__ csr, const float* __restrict__ degI,
    const float* __restrict__ b, float* __restrict__ out)
{
    const int node = blockIdx.x * 4 + (threadIdx.x >> 6);
    if (node >= NN) return;
    const int lane = threadIdx.x & 63;
    const int beg = row_ptr[node], end = row_ptr[node + 1];
    float acc = 0.0f;
    int j = beg;
    for (; j + 3 < end; j += 4) {
        int s0 = csr[j], s1 = csr[j + 1], s2 = csr[j + 2], s3 = csr[j + 3];
        acc += H[(size_t)s0 * 64 + lane] + H[(size_t)s1 * 64 + lane]
             + H[(size_t)s2 * 64 + lane] + H[(size_t)s3 * 64 + lane];
    }
    for (; j < end; ++j) acc += H[(size_t)csr[j] * 64 + lane];
    float o = acc * degI[node] + b[lane];
    if (RELU) o = fmaxf(o, 0.0f);
    out[(size_t)node * 64 + lane] = o;
}

// ---------------------------------------------------------------------------
extern "C" void kernel_launch(void* const* d_in, const int* in_sizes, int n_in,
                              void* d_out, int out_size, void* d_ws, size_t ws_size,
                              hipStream_t stream)
{
    const float* x   = (const float*)d_in[0];
    const int*   src = (const int*)d_in[1];
    const int*   dst = (const int*)d_in[2];
    const float* W1  = (const float*)d_in[3];
    const float* b1  = (const float*)d_in[4];
    const float* W2  = (const float*)d_in[5];
    const float* b2  = (const float*)d_in[6];
    float* out = (float*)d_out;

    // workspace layout (4B units)
    int* w = (int*)d_ws;
    int*   degO_i  = w;                    // 100352 (counts -> in-place rsqrt)
    int*   bktCnt  = w + 100352;           // 512   (memset covers degO_i+bktCnt)
    int*   bktBase = w + 100864;           // 513 (pad 1024)
    int*   bktCur  = w + 101888;           // 512
    int*   row_ptr = w + 102400;           // 100001 (pad 100352)
    float* degI    = (float*)(w + 202752); // 100352
    int*   csr     = w + 303104;           // 1.6M
    float* h1      = (float*)(w + 1903104);   // [NN,128] floats; reused as h2
    int2*  ebuf    = (int2*)h1;               // aliases h1 (dead before gemm1)
    float* agg1    = h1 + (size_t)NN * F1;    // [NN,128]
    const float* degO = (const float*)degO_i;

    hipMemsetAsync(degO_i, 0, (100352 + 512) * sizeof(int), stream);

    // ---- graph preprocessing: bucket-sorted CSR by dst + degrees ----
    bkt_hist<<<(NE + EPB - 1) / EPB, 256, 0, stream>>>(
        (const int4*)src, (const int4*)dst, degO_i, bktCnt);
    bkt_scan<<<1, 512, 0, stream>>>(bktCnt, bktBase, bktCur, row_ptr + NN);
    rsqrtO<<<(NN + 255) / 256, 256, 0, stream>>>(degO_i, NN);
    bkt_scatter<<<(NE + EPB - 1) / EPB, 256, 0, stream>>>(
        (const int4*)src, (const int4*)dst, bktCur, ebuf);
    bkt_csr<<<NBKT, 256, 0, stream>>>(ebuf, bktBase, row_ptr, degI, csr);

    // ---- layer 1 ----
    gemm_rt<F1><<<(NN + 63) / 64, 256, 0, stream>>>(x, W1, degO, h1, NN);
    pull128<true><<<(NN + 3) / 4, 256, 0, stream>>>(h1, row_ptr, csr, degI, b1, agg1);

    // ---- layer 2 ----
    gemm_rt<F2><<<(NN + 127) / 128, 256, 0, stream>>>(agg1, W2, degO, h1, NN);
    pull64<false><<<(NN + 3) / 4, 256, 0, stream>>>(h1, row_ptr, csr, degI, b2, out);
}

// Round 10
// 452.929 us; speedup vs baseline: 9.9401x; 1.0956x over previous
//
#include <hip/hip_runtime.h>
#include <hip/hip_bf16.h>

// Problem constants (from reference)
#define NN 100000      // nodes
#define NE 1600000     // edges
#define KF 128         // in feats == hidden
#define F1 128         // layer-1 out feats
#define F2 64          // layer-2 out feats

#define BSHIFT 8                        // 256 nodes per bucket
#define NBKT ((NN + 255) >> BSHIFT)     // 391 buckets
#define EPB 2048                        // edges per block, phases A/C
#define N4 (NE / 4)                     // 400000 int4 edge-packs

// ---------------------------------------------------------------------------
// Phase A: LDS bucket histogram (by dst>>8) + fused src out-degree count
__global__ __launch_bounds__(256) void bkt_hist(
    const int4* __restrict__ src4, const int4* __restrict__ dst4,
    int* __restrict__ cntO, int* __restrict__ bktCnt)
{
    __shared__ int h[512];
    const int t = threadIdx.x;
    for (int i = t; i < 512; i += 256) h[i] = 0;
    __syncthreads();
    #pragma unroll
    for (int r = 0; r < EPB / 4 / 256; ++r) {           // 2 iters
        int i = blockIdx.x * (EPB / 4) + r * 256 + t;
        if (i < N4) {
            int4 s = src4[i]; int4 d = dst4[i];
            atomicAdd(&cntO[s.x], 1); atomicAdd(&cntO[s.y], 1);
            atomicAdd(&cntO[s.z], 1); atomicAdd(&cntO[s.w], 1);
            atomicAdd(&h[d.x >> BSHIFT], 1); atomicAdd(&h[d.y >> BSHIFT], 1);
            atomicAdd(&h[d.z >> BSHIFT], 1); atomicAdd(&h[d.w >> BSHIFT], 1);
        }
    }
    __syncthreads();
    for (int i = t; i < 512; i += 256)
        if (h[i]) atomicAdd(&bktCnt[i], h[i]);
}

// Phase B: exclusive scan of 512 bucket counts -> bases + cursors; row_ptr[NN]=NE
__global__ __launch_bounds__(512) void bkt_scan(
    const int* __restrict__ bktCnt, int* __restrict__ bktBase,
    int* __restrict__ bktCur, int* __restrict__ row_ptr_end)
{
    __shared__ int s[512];
    const int t = threadIdx.x;
    int v = bktCnt[t];
    s[t] = v; __syncthreads();
    for (int off = 1; off < 512; off <<= 1) {
        int x = (t >= off) ? s[t - off] : 0;
        __syncthreads();
        s[t] += x;
        __syncthreads();
    }
    int excl = s[t] - v;
    bktBase[t] = excl;
    bktCur[t] = excl;
    if (t == 511) { bktBase[512] = s[511]; *row_ptr_end = s[511]; }  // == NE
}

// Phase C: scatter edges into bucket-contiguous ebuf as (dst, src)
__global__ __launch_bounds__(256) void bkt_scatter(
    const int4* __restrict__ src4, const int4* __restrict__ dst4,
    int* __restrict__ bktCur, int2* __restrict__ ebuf)
{
    __shared__ int h[512], bb[512], cur[512];
    const int t = threadIdx.x;
    for (int i = t; i < 512; i += 256) h[i] = 0;
    __syncthreads();
    #pragma unroll
    for (int r = 0; r < EPB / 4 / 256; ++r) {
        int i = blockIdx.x * (EPB / 4) + r * 256 + t;
        if (i < N4) {
            int4 d = dst4[i];
            atomicAdd(&h[d.x >> BSHIFT], 1); atomicAdd(&h[d.y >> BSHIFT], 1);
            atomicAdd(&h[d.z >> BSHIFT], 1); atomicAdd(&h[d.w >> BSHIFT], 1);
        }
    }
    __syncthreads();
    for (int i = t; i < 512; i += 256) {
        bb[i] = h[i] ? atomicAdd(&bktCur[i], h[i]) : 0;
        cur[i] = 0;
    }
    __syncthreads();
    #pragma unroll
    for (int r = 0; r < EPB / 4 / 256; ++r) {
        int i = blockIdx.x * (EPB / 4) + r * 256 + t;
        if (i < N4) {
            int4 s = src4[i]; int4 d = dst4[i];
            int b0 = d.x >> BSHIFT, b1 = d.y >> BSHIFT;
            int b2 = d.z >> BSHIFT, b3 = d.w >> BSHIFT;
            int l0 = atomicAdd(&cur[b0], 1);
            int l1 = atomicAdd(&cur[b1], 1);
            int l2 = atomicAdd(&cur[b2], 1);
            int l3 = atomicAdd(&cur[b3], 1);
            ebuf[bb[b0] + l0] = make_int2(d.x, s.x);
            ebuf[bb[b1] + l1] = make_int2(d.y, s.y);
            ebuf[bb[b2] + l2] = make_int2(d.z, s.z);
            ebuf[bb[b3] + l3] = make_int2(d.w, s.w);
        }
    }
}

// Phase D: per-bucket local CSR via LDS count/scan/cursor; writes row_ptr, degI,
// degO (in-place rsqrt of cntO), csr
__global__ __launch_bounds__(256) void bkt_csr(
    const int2* __restrict__ ebuf, const int* __restrict__ bktBase,
    int* __restrict__ row_ptr, float* __restrict__ degI, int* __restrict__ cntO,
    int* __restrict__ csr)
{
    const int b = blockIdx.x;               // 0..NBKT-1
    const int node0 = b << BSHIFT;
    const int ebase = bktBase[b];
    const int ecnt  = bktBase[b + 1] - ebase;
    __shared__ int cnt[256], sc[256], cur[256];
    const int t = threadIdx.x;
    cnt[t] = 0; __syncthreads();
    for (int i = t; i < ecnt; i += 256)
        atomicAdd(&cnt[ebuf[ebase + i].x - node0], 1);
    __syncthreads();
    int v = cnt[t];
    sc[t] = v; __syncthreads();
    for (int off = 1; off < 256; off <<= 1) {
        int x = (t >= off) ? sc[t - off] : 0;
        __syncthreads();
        sc[t] += x;
        __syncthreads();
    }
    int excl = sc[t] - v;
    int node = node0 + t;
    if (node < NN) {
        row_ptr[node] = ebase + excl;
        degI[node] = rsqrtf(fmaxf((float)v, 1.0f));
        int c = cntO[node];
        reinterpret_cast<float*>(cntO)[node] = rsqrtf(fmaxf((float)c, 1.0f));
    }
    cur[t] = excl; __syncthreads();
    for (int i = t; i < ecnt; i += 256) {
        int2 e = ebuf[ebase + i];
        int slot = atomicAdd(&cur[e.x - node0], 1);
        csr[ebase + slot] = e.y;
    }
}

// ---------------------------------------------------------------------------
// Register-tiled GEMM, bf16 output: Hb[i,j] = bf16(scale[i] * sum_k X[i,k]*W[k,j])
template<int NOUT>
__global__ __launch_bounds__(256) void gemm_rt(
    const float* __restrict__ X, const float* __restrict__ W,
    const float* __restrict__ scale, ushort* __restrict__ Hb, int nrows)
{
    constexpr int K = KF, KC = 32, TN = 8, TM = 4;
    constexpr int CG = NOUT / TN;
    constexpr int RG = 256 / CG;
    constexpr int BM = RG * TM;
    constexpr int XP = KC + 4;

    __shared__ float Xs[2][BM][XP];
    __shared__ float Ws[2][KC][NOUT];

    const int t = threadIdx.x;
    const int cg = t % CG, rg = t / CG;
    const int row0 = blockIdx.x * BM;

    constexpr int XL = BM * (KC / 4) / 256;
    constexpr int WL = KC * (NOUT / 4) / 256;

    float acc[TM][TN];
    #pragma unroll
    for (int i = 0; i < TM; ++i)
        #pragma unroll
        for (int j = 0; j < TN; ++j) acc[i][j] = 0.0f;

    auto load_chunk = [&](int buf, int kc) {
        #pragma unroll
        for (int j = 0; j < XL; ++j) {
            int idx = t + j * 256;
            int r = idx >> 3, kq = idx & 7;
            int gr = min(row0 + r, nrows - 1);
            float4 v = reinterpret_cast<const float4*>(X + (size_t)gr * K + kc)[kq];
            *reinterpret_cast<float4*>(&Xs[buf][r][kq * 4]) = v;
        }
        #pragma unroll
        for (int j = 0; j < WL; ++j) {
            int idx = t + j * 256;
            int kr = idx / (NOUT / 4), c4 = idx % (NOUT / 4);
            float4 v = reinterpret_cast<const float4*>(W + (size_t)(kc + kr) * NOUT)[c4];
            *reinterpret_cast<float4*>(&Ws[buf][kr][c4 * 4]) = v;
        }
    };

    load_chunk(0, 0);
    int buf = 0;
    for (int kc = 0; kc < K; kc += KC) {
        __syncthreads();
        if (kc + KC < K) load_chunk(buf ^ 1, kc + KC);
        #pragma unroll
        for (int k = 0; k < KC; ++k) {
            float w[TN], a[TM];
            *reinterpret_cast<float4*>(&w[0]) =
                *reinterpret_cast<const float4*>(&Ws[buf][k][cg * TN]);
            *reinterpret_cast<float4*>(&w[4]) =
                *reinterpret_cast<const float4*>(&Ws[buf][k][cg * TN + 4]);
            #pragma unroll
            for (int i = 0; i < TM; ++i) a[i] = Xs[buf][rg * TM + i][k];
            #pragma unroll
            for (int i = 0; i < TM; ++i)
                #pragma unroll
                for (int j = 0; j < TN; ++j)
                    acc[i][j] += a[i] * w[j];
        }
        buf ^= 1;
    }

    #pragma unroll
    for (int i = 0; i < TM; ++i) {
        int r = row0 + rg * TM + i;
        if (r < nrows) {
            float s = scale[r];
            uint u[4];
            #pragma unroll
            for (int q = 0; q < 4; ++q) {
                __hip_bfloat162 p = __float22bfloat162_rn(
                    make_float2(acc[i][2 * q] * s, acc[i][2 * q + 1] * s));
                __builtin_memcpy(&u[q], &p, 4);
            }
            uint4 vv = make_uint4(u[0], u[1], u[2], u[3]);
            *reinterpret_cast<uint4*>(Hb + (size_t)r * NOUT + cg * TN) = vv;
        }
    }
}

// ---------------------------------------------------------------------------
// pull aggregation, 128 bf16 feats: one wave per node, lane owns a bfloat162.
// out[d,:] = (sum_{s in N(d)} H[s,:]) * degI[d] + b  (+relu), f32 out
template<bool RELU>
__global__ __launch_bounds__(256) void pull128b(
    const ushort* __restrict__ Hb, const int* __restrict__ row_ptr,
    const int* __restrict__ csr, const float* __restrict__ degI,
    const float* __restrict__ b, float* __restrict__ out)
{
    const int node = blockIdx.x * 4 + (threadIdx.x >> 6);
    if (node >= NN) return;
    const int lane = threadIdx.x & 63;
    const int beg = row_ptr[node], end = row_ptr[node + 1];
    const __hip_bfloat162* __restrict__ H2 =
        reinterpret_cast<const __hip_bfloat162*>(Hb);
    float ax = 0.0f, ay = 0.0f;
    int j = beg;
    for (; j + 3 < end; j += 4) {
        int s0 = csr[j], s1 = csr[j + 1], s2 = csr[j + 2], s3 = csr[j + 3];
        float2 f0 = __bfloat1622float2(H2[(size_t)s0 * 64 + lane]);
        float2 f1 = __bfloat1622float2(H2[(size_t)s1 * 64 + lane]);
        float2 f2 = __bfloat1622float2(H2[(size_t)s2 * 64 + lane]);
        float2 f3 = __bfloat1622float2(H2[(size_t)s3 * 64 + lane]);
        ax += f0.x + f1.x + f2.x + f3.x;
        ay += f0.y + f1.y + f2.y + f3.y;
    }
    for (; j < end; ++j) {
        float2 f = __bfloat1622float2(H2[(size_t)csr[j] * 64 + lane]);
        ax += f.x; ay += f.y;
    }
    const float sc = degI[node];
    const float2 bb = reinterpret_cast<const float2*>(b)[lane];
    float ox = ax * sc + bb.x, oy = ay * sc + bb.y;
    if (RELU) { ox = fmaxf(ox, 0.0f); oy = fmaxf(oy, 0.0f); }
    reinterpret_cast<float2*>(out)[(size_t)node * 64 + lane] = make_float2(ox, oy);
}

// pull aggregation, 64 bf16 feats: one wave per node, half-wave per edge.
// lanes 0-31 handle even-index edges, 32-63 odd; combine via shfl_xor(32).
template<bool RELU>
__global__ __launch_bounds__(256) void pull64b(
    const ushort* __restrict__ Hb, const int* __restrict__ row_ptr,
    const int* __restrict__ csr, const float* __restrict__ degI,
    const float* __restrict__ b, float* __restrict__ out)
{
    const int node = blockIdx.x * 4 + (threadIdx.x >> 6);
    if (node >= NN) return;
    const int lane = threadIdx.x & 63;
    const int half = lane >> 5, l32 = lane & 31;
    const int beg = row_ptr[node], end = row_ptr[node + 1];
    const __hip_bfloat162* __restrict__ H2 =
        reinterpret_cast<const __hip_bfloat162*>(Hb);
    float ax = 0.0f, ay = 0.0f;
    int j = beg;
    for (; j + 3 < end; j += 4) {
        int sA = csr[j + half];
        int sB = csr[j + 2 + half];
        float2 fA = __bfloat1622float2(H2[(size_t)sA * 32 + l32]);
        float2 fB = __bfloat1622float2(H2[(size_t)sB * 32 + l32]);
        ax += fA.x + fB.x; ay += fA.y + fB.y;
    }
    for (; j + 1 < end; j += 2) {
        int s = csr[j + half];
        float2 f = __bfloat1622float2(H2[(size_t)s * 32 + l32]);
        ax += f.x; ay += f.y;
    }
    if (j < end && half == 0) {
        float2 f = __bfloat1622float2(H2[(size_t)csr[j] * 32 + l32]);
        ax += f.x; ay += f.y;
    }
    ax += __shfl_xor(ax, 32);
    ay += __shfl_xor(ay, 32);
    if (half == 0) {
        const float sc = degI[node];
        const float2 bb = reinterpret_cast<const float2*>(b)[l32];
        float ox = ax * sc + bb.x, oy = ay * sc + bb.y;
        if (RELU) { ox = fmaxf(ox, 0.0f); oy = fmaxf(oy, 0.0f); }
        reinterpret_cast<float2*>(out)[(size_t)node * 32 + l32] = make_float2(ox, oy);
    }
}

// ---------------------------------------------------------------------------
extern "C" void kernel_launch(void* const* d_in, const int* in_sizes, int n_in,
                              void* d_out, int out_size, void* d_ws, size_t ws_size,
                              hipStream_t stream)
{
    const float* x   = (const float*)d_in[0];
    const int*   src = (const int*)d_in[1];
    const int*   dst = (const int*)d_in[2];
    const float* W1  = (const float*)d_in[3];
    const float* b1  = (const float*)d_in[4];
    const float* W2  = (const float*)d_in[5];
    const float* b2  = (const float*)d_in[6];
    float* out = (float*)d_out;

    // workspace layout (4B units)
    int* w = (int*)d_ws;
    int*    degO_i  = w;                        // 100352 (counts -> in-place rsqrt)
    int*    bktCnt  = w + 100352;               // 512 (memset covers degO_i+bktCnt)
    int*    bktBase = w + 100864;               // 513 (pad 1024)
    int*    bktCur  = w + 101888;               // 512
    int*    row_ptr = w + 102400;               // 100001 (pad 100352)
    float*  degI    = (float*)(w + 202752);     // 100352
    int*    csr     = w + 303104;               // 1.6M
    ushort* h1b     = (ushort*)(w + 1903104);   // [NN,128] bf16 (6.4M words); reused as h2b
    int2*   ebuf    = (int2*)h1b;               // aliases h1b (dead before gemm1)
    float*  agg1    = (float*)(w + 8303104);    // [NN,128] f32
    const float* degO = (const float*)degO_i;

    hipMemsetAsync(degO_i, 0, (100352 + 512) * sizeof(int), stream);

    // ---- graph preprocessing: bucket-sorted CSR by dst + degrees ----
    bkt_hist<<<(NE + EPB - 1) / EPB, 256, 0, stream>>>(
        (const int4*)src, (const int4*)dst, degO_i, bktCnt);
    bkt_scan<<<1, 512, 0, stream>>>(bktCnt, bktBase, bktCur, row_ptr + NN);
    bkt_scatter<<<(NE + EPB - 1) / EPB, 256, 0, stream>>>(
        (const int4*)src, (const int4*)dst, bktCur, ebuf);
    bkt_csr<<<NBKT, 256, 0, stream>>>(ebuf, bktBase, row_ptr, degI, degO_i, csr);

    // ---- layer 1 ----
    gemm_rt<F1><<<(NN + 63) / 64, 256, 0, stream>>>(x, W1, degO, h1b, NN);
    pull128b<true><<<(NN + 3) / 4, 256, 0, stream>>>(h1b, row_ptr, csr, degI, b1, agg1);

    // ---- layer 2 ----
    gemm_rt<F2><<<(NN + 127) / 128, 256, 0, stream>>>(agg1, W2, degO, h1b, NN);
    pull64b<false><<<(NN + 3) / 4, 256, 0, stream>>>(h1b, row_ptr, csr, degI, b2, out);
}